// Round 1
// baseline (409.669 us; speedup 1.0000x reference)
//
#include <hip/hip_runtime.h>
#include <hip/hip_bf16.h>

#define BATCH 131072
#define DH 128
#define D3 384

typedef float   f32x4  __attribute__((ext_vector_type(4)));
typedef __bf16  bf16x8 __attribute__((ext_vector_type(8)));
typedef unsigned short u16x8 __attribute__((ext_vector_type(8)));

__device__ __forceinline__ unsigned short f2bf(float f) {
    // round-to-nearest-even f32 -> bf16 (inputs are finite)
    unsigned u = __builtin_bit_cast(unsigned, f);
    u += 0x7fffu + ((u >> 16) & 1u);
    return (unsigned short)(u >> 16);
}

__device__ __forceinline__ float fast_tanh(float v) {
    float e = __expf(2.0f * v);
    return (e - 1.0f) * __builtin_amdgcn_rcpf(e + 1.0f);
}
__device__ __forceinline__ float fast_sigmoid(float z) {
    return __builtin_amdgcn_rcpf(1.0f + __expf(-z));
}

// W (f32, [128][384] row-major) -> Wt (bf16 bits, [384][128] row-major)
__global__ void prep_kernel(const float* __restrict__ W, unsigned short* __restrict__ wt) {
    int i   = blockIdx.x * 256 + threadIdx.x;   // 0 .. 49151
    int col = i >> 7;                           // 0 .. 383
    int k   = i & 127;                          // 0 .. 127
    wt[i] = f2bf(W[k * D3 + col]);
}

__global__ __launch_bounds__(256) void fused_kernel(
    const float* __restrict__ h, const float* __restrict__ x,
    const unsigned short* __restrict__ wt, float* __restrict__ out)
{
    const int wave = (blockIdx.x * 256 + (int)threadIdx.x) >> 6;  // 0..8191
    const int lane = threadIdx.x & 63;
    const int c    = lane & 15;   // A row / C col
    const int g    = lane >> 4;   // k-group
    const int R    = wave * 16;   // batch-row base of this 16-row tile

    // ---- A fragments: rows R..R+15 of h, K = 128 (4 k-steps of 32) ----
    // slot mapping (consistent with B): lane group g, reg j -> k = 32*s + 8*g + j
    bf16x8 a[4];
    {
        const float* hrow = h + (size_t)(R + c) * DH;
        #pragma unroll
        for (int s = 0; s < 4; ++s) {
            const float4* p = reinterpret_cast<const float4*>(hrow + 32 * s + 8 * g);
            float4 u0 = p[0], u1 = p[1];
            u16x8 t;
            t[0]=f2bf(u0.x); t[1]=f2bf(u0.y); t[2]=f2bf(u0.z); t[3]=f2bf(u0.w);
            t[4]=f2bf(u1.x); t[5]=f2bf(u1.y); t[6]=f2bf(u1.z); t[7]=f2bf(u1.w);
            a[s] = __builtin_bit_cast(bf16x8, t);
        }
    }

    // ---- accumulators: 24 col-frags (384 cols / 16) ----
    f32x4 acc[24];
    #pragma unroll
    for (int i = 0; i < 24; ++i) acc[i] = (f32x4){0.f, 0.f, 0.f, 0.f};

    // ---- MFMA: B frags streamed from L2-resident Wt ----
    #pragma unroll
    for (int n = 0; n < 24; ++n) {
        const u16x8* wp = reinterpret_cast<const u16x8*>(wt + (16 * n + c) * DH);
        #pragma unroll
        for (int s = 0; s < 4; ++s) {
            u16x8 bv = wp[4 * s + g];   // 8 consecutive bf16: Wt[16n+c][32s+8g .. +8]
            acc[n] = __builtin_amdgcn_mfma_f32_16x16x32_bf16(
                a[s], __builtin_bit_cast(bf16x8, bv), acc[n], 0, 0, 0);
        }
    }

    // ---- epilogue: C/D layout col = lane&15, row = 4*(lane>>4) + reg ----
    const size_t ybase = (size_t)BATCH * DH;
    #pragma unroll
    for (int j = 0; j < 4; ++j) {
        const int row = R + 4 * g + j;
        const float* xr = x + (size_t)row * D3;
        const float* hr = h + (size_t)row * DH;
        float* o0 = out + (size_t)row * DH;
        float* o1 = out + ybase + (size_t)row * DH;
        #pragma unroll
        for (int n = 0; n < 8; ++n) {
            const int d = 16 * n + c;
            float r0 = acc[n][j];
            float r1 = acc[8 + n][j];
            float r2 = acc[16 + n][j];
            float hv = hr[d];
            float it = fast_tanh(xr[d] + r0);
            float ig = fast_sigmoid(xr[DH + d] + r1);
            float og = fast_sigmoid(xr[2 * DH + d] + r2);
            float hn = it * ig + hv * (1.0f - ig);
            o0[d] = hn;
            o1[d] = fast_tanh(hn) * og;
        }
    }
}

extern "C" void kernel_launch(void* const* d_in, const int* in_sizes, int n_in,
                              void* d_out, int out_size, void* d_ws, size_t ws_size,
                              hipStream_t stream) {
    const float* h = (const float*)d_in[0];
    const float* x = (const float*)d_in[1];
    const float* W = (const float*)d_in[2];
    float* out = (float*)d_out;
    unsigned short* wt = (unsigned short*)d_ws;   // 384*128 bf16 = 96 KiB

    prep_kernel<<<192, 256, 0, stream>>>(W, wt);                 // 49152 = 192*256
    fused_kernel<<<BATCH / 16 / 4, 256, 0, stream>>>(h, x, wt, out); // 2048 wg x 4 waves
}